// Round 4
// baseline (359.584 us; speedup 1.0000x reference)
//
#include <hip/hip_runtime.h>
#include <hip/hip_bf16.h>
#include <stdint.h>

// CIGTLayer: fp8 block-quant roundtrips + gating + 4-path batched GEMM.
// N=32768, D=1024, P=4, Fp=256, F=1024.
// ws layout: xd bf16 [N][1024] | Bt bf16 [1024][1024] (f-major, = B^T) | pw f32 [N][4]

typedef float v2f __attribute__((ext_vector_type(2)));
typedef float f32x4 __attribute__((ext_vector_type(4)));
typedef __bf16 bf16x8 __attribute__((ext_vector_type(8)));
typedef unsigned short us4 __attribute__((ext_vector_type(4)));

__device__ __forceinline__ unsigned short f2bf(float f) {
  // round-to-nearest-even f32 -> bf16 (finite inputs only)
  unsigned u = __builtin_bit_cast(unsigned, f);
  u += 0x7fffu + ((u >> 16) & 1u);
  return (unsigned short)(u >> 16);
}

// fp8 e4m3fn roundtrip, true f32 division (used on tiny one-time paths).
__device__ __forceinline__ v2f fp8_rt2s(float a, float b, float sa, float sb) {
  int q = __builtin_amdgcn_cvt_pk_fp8_f32(a / sa, b / sb, 0, false);
  v2f r = __builtin_amdgcn_cvt_pk_f32_fp8(q, false);
  r.x *= sa;
  r.y *= sb;
  return r;
}

// fp8 roundtrip with precomputed scale + reciprocal (hot path).
__device__ __forceinline__ v2f fp8_rt2i(float a, float b, float s, float inv) {
  int q = __builtin_amdgcn_cvt_pk_fp8_f32(a * inv, b * inv, 0, false);
  v2f r = __builtin_amdgcn_cvt_pk_f32_fp8(q, false);
  r.x *= s;
  r.y *= s;
  return r;
}

__device__ __forceinline__ unsigned pk_bf16(float lo, float hi) {
  unsigned r;
  asm("v_cvt_pk_bf16_f32 %0, %1, %2" : "=v"(r) : "v"(lo), "v"(hi));
  return r;
}

__device__ __forceinline__ void g2l16(const void* g, void* l) {
  __builtin_amdgcn_global_load_lds(
      (const __attribute__((address_space(1))) unsigned int*)g,
      (__attribute__((address_space(3))) unsigned int*)l,
      16, 0, 0);
}

// ---------------------------------------------------------------------------
// Kernel 1: quantize x (block=128 along D), write bf16 xd, compute info gating.
// One wave per row. Lane l owns d in [16l, 16l+16): one 128-elem quant block
// per 8-lane group -> absmax reduce is 3 shfls. rcp instead of f32 division.
// All-lane sigmoid tail (no serial lane-0 region).
// ---------------------------------------------------------------------------
__global__ __launch_bounds__(256) void k_quant_info(
    const float* __restrict__ x, const float* __restrict__ ik,
    const float* __restrict__ ib, unsigned short* __restrict__ xd,
    float* __restrict__ pw, float* __restrict__ cumul, int N) {
  const int tid = threadIdx.x;
  const int lane = tid & 63, wv = tid >> 6;
  const int gw = blockIdx.x * 4 + wv;
  const int nw = gridDim.x * 4;

  // Preload dequantized info_kernel rows for d in [16*lane, 16*lane+16).
  // (ik quant block = min(128,4) = 4 -> per-row-of-4 scale; one-time cost,
  // keep exact division.)
  f32x4 kv[16];
#pragma unroll
  for (int q = 0; q < 16; ++q) {
    const int d = lane * 16 + q;
    f32x4 v = ((const f32x4*)ik)[d];
    float m = fmaxf(fmaxf(fabsf(v.x), fabsf(v.y)), fmaxf(fabsf(v.z), fabsf(v.w)));
    float s = fmaxf(m * (1.0f / 448.0f), 1e-12f);
    v2f lo = fp8_rt2s(v.x, v.y, s, s);
    v2f hi = fp8_rt2s(v.z, v.w, s, s);
    f32x4 dq; dq.x = lo.x; dq.y = lo.y; dq.z = hi.x; dq.w = hi.y;
    kv[q] = dq;
  }
  const f32x4 ibv = *(const f32x4*)ib;

  for (int row = gw; row < N; row += nw) {
    const f32x4* xr = (const f32x4*)(x + (size_t)row * 1024) + lane * 4;
    f32x4 v0 = xr[0], v1 = xr[1], v2 = xr[2], v3 = xr[3];

    // per-lane absmax of 16, then 8-lane-group (=128-block) reduce
    float m = fmaxf(fmaxf(fabsf(v0.x), fabsf(v0.y)), fmaxf(fabsf(v0.z), fabsf(v0.w)));
    m = fmaxf(m, fmaxf(fmaxf(fabsf(v1.x), fabsf(v1.y)), fmaxf(fabsf(v1.z), fabsf(v1.w))));
    m = fmaxf(m, fmaxf(fmaxf(fabsf(v2.x), fabsf(v2.y)), fmaxf(fabsf(v2.z), fabsf(v2.w))));
    m = fmaxf(m, fmaxf(fmaxf(fabsf(v3.x), fabsf(v3.y)), fmaxf(fabsf(v3.z), fabsf(v3.w))));
    m = fmaxf(m, __shfl_xor(m, 1, 64));
    m = fmaxf(m, __shfl_xor(m, 2, 64));
    m = fmaxf(m, __shfl_xor(m, 4, 64));
    const float s = fmaxf(m * (1.0f / 448.0f), 1e-12f);
    const float inv = __builtin_amdgcn_rcpf(s);

    float p0 = 0.f, p1 = 0.f, p2 = 0.f, p3 = 0.f;
    unsigned w[8];
#define QPAIR(J, A, B)                                            \
    {                                                             \
      v2f r = fp8_rt2i((A), (B), s, inv);                         \
      f32x4 ka = kv[2 * (J)], kb = kv[2 * (J) + 1];               \
      p0 += r.x * ka.x + r.y * kb.x;                              \
      p1 += r.x * ka.y + r.y * kb.y;                              \
      p2 += r.x * ka.z + r.y * kb.z;                              \
      p3 += r.x * ka.w + r.y * kb.w;                              \
      w[J] = pk_bf16(r.x, r.y);                                   \
    }
    QPAIR(0, v0.x, v0.y) QPAIR(1, v0.z, v0.w)
    QPAIR(2, v1.x, v1.y) QPAIR(3, v1.z, v1.w)
    QPAIR(4, v2.x, v2.y) QPAIR(5, v2.z, v2.w)
    QPAIR(6, v3.x, v3.y) QPAIR(7, v3.z, v3.w)
#undef QPAIR

    // store 32 contiguous bytes per lane
    uint4* dst = (uint4*)(xd + (size_t)row * 1024 + lane * 16);
    uint4 o0; o0.x = w[0]; o0.y = w[1]; o0.z = w[2]; o0.w = w[3];
    uint4 o1; o1.x = w[4]; o1.y = w[5]; o1.z = w[6]; o1.w = w[7];
    dst[0] = o0; dst[1] = o1;

    // full-wave reduce of the 4 path dots
#pragma unroll
    for (int off = 1; off <= 32; off <<= 1) {
      p0 += __shfl_xor(p0, off, 64);
      p1 += __shfl_xor(p1, off, 64);
      p2 += __shfl_xor(p2, off, 64);
      p3 += __shfl_xor(p3, off, 64);
    }

    // all lanes compute; lanes 0..3 store path (lane&3)
    const int pl = lane & 3;
    float pv = p0;
    pv = (pl == 1) ? p1 : pv;
    pv = (pl == 2) ? p2 : pv;
    pv = (pl == 3) ? p3 : pv;
    float bb = ibv.x;
    bb = (pl == 1) ? ibv.y : bb;
    bb = (pl == 2) ? ibv.z : bb;
    bb = (pl == 3) ? ibv.w : bb;
    float g = __builtin_amdgcn_rcpf(1.f + __expf(-(pv + bb)));
    float wgt = __builtin_amdgcn_rcpf(1.f + __expf(-((g - 0.1f) * 10.f)));
    if (lane < 4) {
      cumul[(size_t)row * 4 + pl] = g;
      pw[(size_t)row * 4 + pl] = wgt;
    }
  }
}

// ---------------------------------------------------------------------------
// Kernel 2: roundtrip path_kernels [4][1024][256] (quant block=128 along f),
// write transposed Bt[f_global][d] bf16, f_global = p*256 + f.
// Block handles (p, 32 d-rows). grid = 4*32 = 128 blocks.
// Scales computed from load registers via shfl.
// ---------------------------------------------------------------------------
__global__ __launch_bounds__(256) void k_quant_pk(
    const float* __restrict__ pk, unsigned short* __restrict__ bt) {
  __shared__ float s_x[32 * 256];
  __shared__ float s_s[32 * 2];
  const int tid = threadIdx.x;
  const int lane = tid & 63, wv = tid >> 6;
  const int p = blockIdx.x >> 5;
  const int d0 = (blockIdx.x & 31) * 32;

  const f32x4* src = (const f32x4*)(pk + ((size_t)p * 1024 + d0) * 256);
  f32x4* dst = (f32x4*)s_x;
#pragma unroll
  for (int i = 0; i < 8; ++i) {
    f32x4 v = src[tid + i * 256];
    dst[tid + i * 256] = v;
    float m = fmaxf(fmaxf(fabsf(v.x), fabsf(v.y)), fmaxf(fabsf(v.z), fabsf(v.w)));
#pragma unroll
    for (int off = 1; off <= 16; off <<= 1)
      m = fmaxf(m, __shfl_xor(m, off, 64));  // reduce within 32-lane half
    if ((lane & 31) == 0)
      s_s[(wv + 4 * i) * 2 + (lane >> 5)] = fmaxf(m * (1.0f / 448.0f), 1e-12f);
  }
  __syncthreads();

  const int f = tid;  // 0..255
  uint4 hv[4];
  unsigned* hw = (unsigned*)hv;
#pragma unroll
  for (int d = 0; d < 32; d += 2) {
    float v0 = s_x[d * 256 + f];            // lanes read consecutive f: no conflict
    float sa = s_s[d * 2 + (f >> 7)];
    float v1 = s_x[(d + 1) * 256 + f];
    float sb = s_s[(d + 1) * 2 + (f >> 7)];
    v2f r = fp8_rt2s(v0, v1, sa, sb);
    hw[d >> 1] = (unsigned)f2bf(r.x) | ((unsigned)f2bf(r.y) << 16);
  }
  unsigned short* orow = bt + (size_t)(p * 256 + f) * 1024 + d0;
  uint4* ov = (uint4*)orow;
#pragma unroll
  for (int i = 0; i < 4; ++i) ov[i] = hv[i];
}

// ---------------------------------------------------------------------------
// Kernel 3: C[n][f] = sum_d xd[n][d]*Bt[f][d]; out = (C + pb[f]) * pw[n][f>>8]
// m97 structure: 128x128 tile, BK=64, 4 waves (2x2 of 64x64), 16x16x32 MFMA,
// global_load_lds width-16 staging, two barriers per K-step.
// T1 XCD-aware swizzle: 8 f-tiles sharing an xd strip run on the same XCD.
// ---------------------------------------------------------------------------
__global__ __launch_bounds__(256) void k_gemm(
    const unsigned short* __restrict__ xd, const unsigned short* __restrict__ bt,
    const float* __restrict__ pb, const float* __restrict__ pw,
    float* __restrict__ out, int N) {
  __shared__ __align__(16) unsigned short As[128 * 64];
  __shared__ __align__(16) unsigned short Bs[128 * 64];
  const int tid = threadIdx.x;
  const int lane = tid & 63, wv = tid >> 6;
  // T1: nwg = N/128*8 (divisible by 8). XCD x gets logical tiles [x*cpx,(x+1)*cpx)
  const int nwg = gridDim.x, cpx = nwg >> 3;
  const int bx = (blockIdx.x & 7) * cpx + (blockIdx.x >> 3);
  const int tm = bx >> 3, tn = bx & 7;
  const int m0 = tm * 128, f0 = tn * 128;
  const int wr = wv >> 1, wc = wv & 1;

  f32x4 acc[4][4] = {};
  const int frow = lane & 15;
  const int fk = (lane >> 4) * 8;

  for (int k0 = 0; k0 < 1024; k0 += 64) {
    __syncthreads();
#pragma unroll
    for (int i = 0; i < 4; ++i) {
      const int cbase = (wv * 4 + i) * 64;       // wave-uniform chunk base
      const int chunk = cbase + lane;            // 0..1023, 16B each
      const int r = chunk >> 3, c8 = chunk & 7;
      g2l16(xd + (size_t)(m0 + r) * 1024 + k0 + c8 * 8, (char*)As + cbase * 16);
      g2l16(bt + (size_t)(f0 + r) * 1024 + k0 + c8 * 8, (char*)Bs + cbase * 16);
    }
    __syncthreads();
#pragma unroll
    for (int kk = 0; kk < 64; kk += 32) {
      bf16x8 af[4], bfr[4];
#pragma unroll
      for (int mi = 0; mi < 4; ++mi)
        af[mi] = *(const bf16x8*)&As[(wr * 64 + mi * 16 + frow) * 64 + kk + fk];
#pragma unroll
      for (int ni = 0; ni < 4; ++ni)
        bfr[ni] = *(const bf16x8*)&Bs[(wc * 64 + ni * 16 + frow) * 64 + kk + fk];
#pragma unroll
      for (int mi = 0; mi < 4; ++mi)
#pragma unroll
        for (int ni = 0; ni < 4; ++ni)
          acc[mi][ni] = __builtin_amdgcn_mfma_f32_16x16x32_bf16(
              af[mi], bfr[ni], acc[mi][ni], 0, 0, 0);
    }
  }

  // epilogue: C/D layout col = lane&15, row = (lane>>4)*4 + reg (m89-verified)
  const int r0 = m0 + wr * 64 + (lane >> 4) * 4;
  const int c0 = f0 + wc * 64 + frow;
#pragma unroll
  for (int ni = 0; ni < 4; ++ni) {
    const int c = c0 + ni * 16;
    const float bias = pb[c];
    const int p = c >> 8;
#pragma unroll
    for (int mi = 0; mi < 4; ++mi) {
#pragma unroll
      for (int r = 0; r < 4; ++r) {
        const int row = r0 + mi * 16 + r;
        out[(size_t)row * 1024 + c] = (acc[mi][ni][r] + bias) * pw[row * 4 + p];
      }
    }
  }
}

extern "C" void kernel_launch(void* const* d_in, const int* in_sizes, int n_in,
                              void* d_out, int out_size, void* d_ws, size_t ws_size,
                              hipStream_t stream) {
  const float* x  = (const float*)d_in[0];
  const float* ik = (const float*)d_in[1];
  const float* ib = (const float*)d_in[2];
  const float* pk = (const float*)d_in[3];
  const float* pb = (const float*)d_in[4];
  const int N = in_sizes[0] / 1024;

  float* out = (float*)d_out;
  float* cumul = out + (size_t)N * 1024;

  char* ws = (char*)d_ws;
  unsigned short* xd = (unsigned short*)ws;                                  // N*1024 bf16
  unsigned short* bt = (unsigned short*)(ws + (size_t)N * 1024 * 2);         // 1024*1024 bf16
  float* pw = (float*)(ws + (size_t)N * 1024 * 2 + (size_t)1024 * 1024 * 2); // N*4 f32

  hipLaunchKernelGGL(k_quant_info, dim3(2048), dim3(256), 0, stream,
                     x, ik, ib, xd, pw, cumul, N);
  hipLaunchKernelGGL(k_quant_pk, dim3(128), dim3(256), 0, stream, pk, bt);
  hipLaunchKernelGGL(k_gemm, dim3((N / 128) * 8), dim3(256), 0, stream,
                     xd, bt, pb, pw, out, N);
}